// Round 2
// baseline (397.966 us; speedup 1.0000x reference)
//
#include <hip/hip_runtime.h>
#include <hip/hip_bf16.h>

// MAB block: q/k/v proj -> attention(+q residual) -> LN0 -> x + relu(x@Wo^T+bo) -> LN1
// B=16, Lq=Lkv=1024, SIZE=512, H=8, HEAD=64. All fp32 in/out; bf16 MFMA internally.
//
// Workspace layout (bytes), peak 116 MB:
//   [0,16M)    qbf   (query bf16)            -- dead after Q-proj; reused by xf32
//   [16M,32M)  kvbf  (key_value bf16)        -- dead after V-proj; reused by xf32
//   [32M,36M)  Wq/Wk/Wv/Wo bf16 (512KB each)
//   [36M,68M)  qf32  (projected q, fp32)     -- dead after attn; reused by y
//   [68M,84M)  qpbf  (projected q * 1/sqrt(512), bf16)  -- dead after attn
//   [84M,100M) kbf   (projected k, bf16)     -- dead after attn
//   [100M,116M) vtbf (v TRANSPOSED [B][feat][tok], bf16) -- reused by xbf
//   d_out doubles as scratch for out1 = qh + attn (pre-LN0), then holds final LN1.

#define HNUM 8
#define MSIZE 512
#define HEADD 64
#define LQ 1024
#define LKV 1024
#define NBATCH 16

typedef unsigned short u16;
typedef __bf16 bf16_t;
typedef bf16_t bf16x8 __attribute__((ext_vector_type(8)));
typedef float f32x4 __attribute__((ext_vector_type(4)));
typedef u16 u16x8 __attribute__((ext_vector_type(8)));

// float -> bf16 RNE; native cast lets clang emit v_cvt_pk_bf16_f32
__device__ __forceinline__ u16 f2bf(float f) {
  __bf16 h = (__bf16)f;
  u16 r; __builtin_memcpy(&r, &h, 2); return r;
}

// 16B loads via memcpy (avoids TBAA hazards between u16 storage and bf16 vectors)
__device__ __forceinline__ bf16x8 ldb8(const void* p) {
  bf16x8 r; __builtin_memcpy(&r, p, 16); return r;
}
__device__ __forceinline__ float4 ldf4(const float* p) {
  float4 v; __builtin_memcpy(&v, p, 16); return v;
}
__device__ __forceinline__ void stf4(float* p, const float4& v) {
  __builtin_memcpy(p, &v, 16);
}

__device__ __forceinline__ void gload16(const u16* g, u16* l) {
  __builtin_amdgcn_global_load_lds((const __attribute__((address_space(1))) void*)g,
                                   (__attribute__((address_space(3))) void*)l,
                                   16, 0, 0);
}

// ---------------- fp32 -> bf16 converts ----------------

__global__ __launch_bounds__(256) void cvt2_k(const float* __restrict__ a, u16* __restrict__ da,
                                              const float* __restrict__ b, u16* __restrict__ db,
                                              int n) {
  size_t i = ((size_t)blockIdx.x * 256 + threadIdx.x) * 8;
  const float* s; u16* d;
  if (i < (size_t)n) { s = a + i; d = da + i; }
  else               { s = b + (i - n); d = db + (i - n); }
  float4 v0 = ldf4(s), v1 = ldf4(s + 4);
  u16x8 o;
  o[0]=f2bf(v0.x); o[1]=f2bf(v0.y); o[2]=f2bf(v0.z); o[3]=f2bf(v0.w);
  o[4]=f2bf(v1.x); o[5]=f2bf(v1.y); o[6]=f2bf(v1.z); o[7]=f2bf(v1.w);
  __builtin_memcpy(d, &o, 16);
}

__global__ __launch_bounds__(256) void cvt4_k(const float* __restrict__ a0, u16* __restrict__ d0,
                                              const float* __restrict__ a1, u16* __restrict__ d1,
                                              const float* __restrict__ a2, u16* __restrict__ d2,
                                              const float* __restrict__ a3, u16* __restrict__ d3,
                                              int n) {
  size_t i = ((size_t)blockIdx.x * 256 + threadIdx.x) * 8;
  int sel = (int)(i / (size_t)n);
  size_t off = i - (size_t)sel * (size_t)n;
  const float* s = sel == 0 ? a0 : sel == 1 ? a1 : sel == 2 ? a2 : a3;
  u16*         d = sel == 0 ? d0 : sel == 1 ? d1 : sel == 2 ? d2 : d3;
  float4 v0 = ldf4(s + off), v1 = ldf4(s + off + 4);
  u16x8 o;
  o[0]=f2bf(v0.x); o[1]=f2bf(v0.y); o[2]=f2bf(v0.z); o[3]=f2bf(v0.w);
  o[4]=f2bf(v1.x); o[5]=f2bf(v1.y); o[6]=f2bf(v1.z); o[7]=f2bf(v1.w);
  __builtin_memcpy(d + off, &o, 16);
}

// ---------------- GEMM (B^T layout): C[m,n] = sum_k A[m,k]*W[n,k] + bias[n] ----------------
// m97 structure: 128x128 tile, BK=32, 4 waves (2x2), global_load_lds w16, 16 MFMA/K-step.
// MODE 0: outf = C (fp32), outb = bf16(C * 1/sqrt(512))      (q projection)
// MODE 1: outb = bf16(C)                                     (k projection)
// MODE 2: outb transposed [B][feat][tok] via LDS (coalesced) (v projection)
// MODE 3: outf = resid + relu(C)                             (output projection)

template<int MODE>
__global__ __launch_bounds__(256) void gemm_bt_k(
    const u16* __restrict__ A, const u16* __restrict__ W, const float* __restrict__ bias,
    const float* __restrict__ resid, float* __restrict__ outf, u16* __restrict__ outb)
{
  __shared__ u16 As[128 * 32];
  __shared__ u16 Bs[128 * 32];
  const int tid = threadIdx.x;
  const int w = tid >> 6, l = tid & 63;
  const int wr = w >> 1, wc = w & 1;
  const int lo = l & 15, hi = l >> 4;
  const int mb = blockIdx.y, nb = blockIdx.x;

  f32x4 acc[4][4] = {};
  const int s0 = w * 128 + l;

  for (int kt = 0; kt < 16; ++kt) {
    __syncthreads();
#pragma unroll
    for (int c = 0; c < 2; ++c) {
      int s = s0 + c * 64;
      int row = s >> 2, k8 = s & 3;
      const u16* ga = A + (size_t)(mb * 128 + row) * MSIZE + kt * 32 + k8 * 8;
      gload16(ga, &As[(w * 128 + c * 64) * 8]);
      const u16* gw = W + (size_t)(nb * 128 + row) * MSIZE + kt * 32 + k8 * 8;
      gload16(gw, &Bs[(w * 128 + c * 64) * 8]);
    }
    __syncthreads();
    bf16x8 af[4], bfr[4];
#pragma unroll
    for (int i = 0; i < 4; ++i) af[i]  = ldb8(&As[(wr * 64 + i * 16 + lo) * 32 + hi * 8]);
#pragma unroll
    for (int j = 0; j < 4; ++j) bfr[j] = ldb8(&Bs[(wc * 64 + j * 16 + lo) * 32 + hi * 8]);
#pragma unroll
    for (int i = 0; i < 4; ++i)
#pragma unroll
      for (int j = 0; j < 4; ++j)
        acc[i][j] = __builtin_amdgcn_mfma_f32_16x16x32_bf16(af[i], bfr[j], acc[i][j], 0, 0, 0);
  }

  const int nbase = nb * 128 + wc * 64;
  const int mbase = mb * 128 + wr * 64;
  float bj[4];
#pragma unroll
  for (int j = 0; j < 4; ++j) bj[j] = bias[nbase + j * 16 + lo];

  if (MODE == 2) {
    // transposed write via LDS: per j, stage [32 n][128 m] chunk, read back coalesced
    u16* T = As;  // 32*128*2B = 8KB, fits
#pragma unroll
    for (int j = 0; j < 4; ++j) {
      __syncthreads();   // previous chunk's reads (or main loop's) done
#pragma unroll
      for (int i = 0; i < 4; ++i)
#pragma unroll
        for (int e = 0; e < 4; ++e) {
          int n_local = wc * 16 + lo;
          int m_local = wr * 64 + i * 16 + hi * 4 + e;
          T[n_local * 128 + m_local] = f2bf(acc[i][j][e] + bj[j]);
        }
      __syncthreads();
      int n_local = tid >> 3, m0 = (tid & 7) * 16;
      u16x8 r0, r1;
      __builtin_memcpy(&r0, &T[n_local * 128 + m0], 16);
      __builtin_memcpy(&r1, &T[n_local * 128 + m0 + 8], 16);
      int n_global = nb * 128 + (n_local >> 4) * 64 + j * 16 + (n_local & 15);
      int m_global = mb * 128 + m0;
      int bb = m_global >> 10, tt = m_global & 1023;
      u16* dst = outb + ((size_t)bb * MSIZE + n_global) * LKV + tt;
      __builtin_memcpy(dst, &r0, 16);
      __builtin_memcpy(dst + 8, &r1, 16);
    }
    return;
  }

#pragma unroll
  for (int i = 0; i < 4; ++i) {
#pragma unroll
    for (int j = 0; j < 4; ++j) {
#pragma unroll
      for (int e = 0; e < 4; ++e) {
        int m = mbase + i * 16 + hi * 4 + e;     // C/D layout: row=(lane>>4)*4+e
        int n = nbase + j * 16 + lo;             //             col=lane&15
        float v = acc[i][j][e] + bj[j];
        if (MODE == 0) {
          outf[(size_t)m * MSIZE + n] = v;
          outb[(size_t)m * MSIZE + n] = f2bf(v * 0.04419417382415922f); // 1/sqrt(512)
        } else if (MODE == 1) {
          outb[(size_t)m * MSIZE + n] = f2bf(v);
        } else {
          float r = resid[(size_t)m * MSIZE + n];
          outf[(size_t)m * MSIZE + n] = r + fmaxf(v, 0.0f);
        }
      }
    }
  }
}

// ---------------- flash attention + q residual ----------------
// One wave per (b, h, 32 q-rows), KV tile = 64. K/V read straight from global
// (L2-resident per head; blk%8==h keeps one (b,h)'s q-blocks on one XCD).
// q pre-scaled by 1/sqrt(512). out1[m, h*64+d] = qf32 + softmax(qk)·v

__global__ __launch_bounds__(64) void attn_k(
    const u16* __restrict__ q, const u16* __restrict__ kk, const u16* __restrict__ vt,
    const float* __restrict__ qf, float* __restrict__ out1)
{
  __shared__ u16 P[32 * 68];          // stride 68 halves: 16B-aligned, ~4-way max conflicts
  const int l = threadIdx.x;
  const int lo = l & 15, hi = l >> 4;
  const int blk = blockIdx.x;
  const int h = blk & 7, qb = (blk >> 3) & 31, b = blk >> 8;   // XCD-friendly decode

  const u16* qbase = q  + ((size_t)(b * LQ + qb * 32)) * MSIZE + h * HEADD;
  const u16* kbase = kk + (size_t)b * LKV * MSIZE + h * HEADD;
  const u16* vbase = vt + ((size_t)(b * MSIZE + h * HEADD)) * LKV;

  bf16x8 aq[2][2];
#pragma unroll
  for (int mt = 0; mt < 2; ++mt)
#pragma unroll
    for (int kc = 0; kc < 2; ++kc)
      aq[mt][kc] = ldb8(qbase + (size_t)(mt * 16 + lo) * MSIZE + kc * 32 + hi * 8);

  f32x4 acc[2][4] = {};
  float mrun[2][4], lrun[2][4];
#pragma unroll
  for (int mt = 0; mt < 2; ++mt)
#pragma unroll
    for (int e = 0; e < 4; ++e) { mrun[mt][e] = -1e30f; lrun[mt][e] = 0.0f; }

  for (int n0 = 0; n0 < LKV; n0 += 64) {
    f32x4 S[2][4] = {};
#pragma unroll
    for (int half = 0; half < 2; ++half) {         // K regs reused across halves (VGPR cap)
      bf16x8 bk[2][2];
#pragma unroll
      for (int ntl = 0; ntl < 2; ++ntl)
#pragma unroll
        for (int kc = 0; kc < 2; ++kc)
          bk[ntl][kc] = ldb8(kbase + (size_t)(n0 + (half * 2 + ntl) * 16 + lo) * MSIZE + kc * 32 + hi * 8);
#pragma unroll
      for (int mt = 0; mt < 2; ++mt)
#pragma unroll
        for (int ntl = 0; ntl < 2; ++ntl) {
          int nt = half * 2 + ntl;
          S[mt][nt] = __builtin_amdgcn_mfma_f32_16x16x32_bf16(aq[mt][0], bk[ntl][0], S[mt][nt], 0, 0, 0);
          S[mt][nt] = __builtin_amdgcn_mfma_f32_16x16x32_bf16(aq[mt][1], bk[ntl][1], S[mt][nt], 0, 0, 0);
        }
    }

    // online softmax: row = mt*16 + hi*4 + e, cols spread across 16 lanes (lo) x 4 nt
#pragma unroll
    for (int mt = 0; mt < 2; ++mt) {
#pragma unroll
      for (int e = 0; e < 4; ++e) {
        float cm = fmaxf(fmaxf(S[mt][0][e], S[mt][1][e]), fmaxf(S[mt][2][e], S[mt][3][e]));
#pragma unroll
        for (int msk = 1; msk < 16; msk <<= 1) cm = fmaxf(cm, __shfl_xor(cm, msk));
        float mnew = fmaxf(mrun[mt][e], cm);
        float fs = __expf(mrun[mt][e] - mnew);
        mrun[mt][e] = mnew;
        float p0 = __expf(S[mt][0][e] - mnew);
        float p1 = __expf(S[mt][1][e] - mnew);
        float p2 = __expf(S[mt][2][e] - mnew);
        float p3 = __expf(S[mt][3][e] - mnew);
        float rs = (p0 + p1) + (p2 + p3);
#pragma unroll
        for (int msk = 1; msk < 16; msk <<= 1) rs += __shfl_xor(rs, msk);
        lrun[mt][e] = lrun[mt][e] * fs + rs;
#pragma unroll
        for (int dt = 0; dt < 4; ++dt) acc[mt][dt][e] *= fs;
        int pr = (mt * 16 + hi * 4 + e) * 68 + lo;
        P[pr]      = f2bf(p0);
        P[pr + 16] = f2bf(p1);
        P[pr + 32] = f2bf(p2);
        P[pr + 48] = f2bf(p3);
      }
    }
    __syncthreads();                     // P writes -> P reads (cross-lane)

    bf16x8 pa[2][2];
#pragma unroll
    for (int mt = 0; mt < 2; ++mt)
#pragma unroll
      for (int ks = 0; ks < 2; ++ks)
        pa[mt][ks] = ldb8(&P[(mt * 16 + lo) * 68 + ks * 32 + hi * 8]);
    __syncthreads();                     // P reads -> next iter's writes

    // PV: A = P[32 q][64 kv], B = v^T[d][kv] (contiguous thanks to vt layout)
#pragma unroll
    for (int dt = 0; dt < 4; ++dt)
#pragma unroll
      for (int ks = 0; ks < 2; ++ks) {
        bf16x8 bv = ldb8(vbase + (size_t)(dt * 16 + lo) * LKV + n0 + ks * 32 + hi * 8);
#pragma unroll
        for (int mt = 0; mt < 2; ++mt)
          acc[mt][dt] = __builtin_amdgcn_mfma_f32_16x16x32_bf16(pa[mt][ks], bv, acc[mt][dt], 0, 0, 0);
      }
  }

#pragma unroll
  for (int mt = 0; mt < 2; ++mt) {
    float inv[4];
#pragma unroll
    for (int e = 0; e < 4; ++e) inv[e] = 1.0f / lrun[mt][e];
#pragma unroll
    for (int dt = 0; dt < 4; ++dt)
#pragma unroll
      for (int e = 0; e < 4; ++e) {
        size_t m = (size_t)b * LQ + qb * 32 + mt * 16 + hi * 4 + e;
        int n = h * HEADD + dt * 16 + lo;
        float v = acc[mt][dt][e] * inv[e] + qf[m * MSIZE + n];
        out1[m * MSIZE + n] = v;
      }
  }
}

// ---------------- LayerNorm (one wave per 512-wide row) ----------------
// WRITE_BF: also emit bf16 copy (input to the next MFMA GEMM)

template<int WRITE_BF>
__global__ __launch_bounds__(64) void ln_kk(const float* __restrict__ in, const float* __restrict__ g,
                                            const float* __restrict__ be, float* __restrict__ outf,
                                            u16* __restrict__ outb)
{
  const int row = blockIdx.x, l = threadIdx.x;
  const float* p = in + (size_t)row * MSIZE + l * 8;
  float4 v0 = ldf4(p), v1 = ldf4(p + 4);
  float s  = v0.x + v0.y + v0.z + v0.w + v1.x + v1.y + v1.z + v1.w;
  float s2 = 0.0f;
  s2 = fmaf(v0.x, v0.x, s2); s2 = fmaf(v0.y, v0.y, s2);
  s2 = fmaf(v0.z, v0.z, s2); s2 = fmaf(v0.w, v0.w, s2);
  s2 = fmaf(v1.x, v1.x, s2); s2 = fmaf(v1.y, v1.y, s2);
  s2 = fmaf(v1.z, v1.z, s2); s2 = fmaf(v1.w, v1.w, s2);
#pragma unroll
  for (int m = 1; m < 64; m <<= 1) { s += __shfl_xor(s, m); s2 += __shfl_xor(s2, m); }
  float mu   = s * (1.0f / 512.0f);
  float var  = s2 * (1.0f / 512.0f) - mu * mu;
  float rstd = rsqrtf(var + 1e-5f);

  float4 g0 = ldf4(g + l * 8), g1 = ldf4(g + l * 8 + 4);
  float4 b0 = ldf4(be + l * 8), b1 = ldf4(be + l * 8 + 4);
  float4 o0, o1;
  o0.x = (v0.x - mu) * rstd * g0.x + b0.x;  o0.y = (v0.y - mu) * rstd * g0.y + b0.y;
  o0.z = (v0.z - mu) * rstd * g0.z + b0.z;  o0.w = (v0.w - mu) * rstd * g0.w + b0.w;
  o1.x = (v1.x - mu) * rstd * g1.x + b1.x;  o1.y = (v1.y - mu) * rstd * g1.y + b1.y;
  o1.z = (v1.z - mu) * rstd * g1.z + b1.z;  o1.w = (v1.w - mu) * rstd * g1.w + b1.w;
  float* q = outf + (size_t)row * MSIZE + l * 8;
  stf4(q, o0); stf4(q + 4, o1);
  if (WRITE_BF) {
    u16x8 ob;
    ob[0]=f2bf(o0.x); ob[1]=f2bf(o0.y); ob[2]=f2bf(o0.z); ob[3]=f2bf(o0.w);
    ob[4]=f2bf(o1.x); ob[5]=f2bf(o1.y); ob[6]=f2bf(o1.z); ob[7]=f2bf(o1.w);
    __builtin_memcpy(outb + (size_t)row * MSIZE + l * 8, &ob, 16);
  }
}

// ---------------- launch ----------------

extern "C" void kernel_launch(void* const* d_in, const int* in_sizes, int n_in,
                              void* d_out, int out_size, void* d_ws, size_t ws_size,
                              hipStream_t stream) {
  const float* query = (const float*)d_in[0];
  const float* keyv  = (const float*)d_in[1];
  const float* Wq = (const float*)d_in[2];  const float* bq = (const float*)d_in[3];
  const float* Wk = (const float*)d_in[4];  const float* bk = (const float*)d_in[5];
  const float* Wv = (const float*)d_in[6];  const float* bv = (const float*)d_in[7];
  const float* Wo = (const float*)d_in[8];  const float* bo = (const float*)d_in[9];
  const float* g0 = (const float*)d_in[10]; const float* b0 = (const float*)d_in[11];
  const float* g1 = (const float*)d_in[12]; const float* b1 = (const float*)d_in[13];
  float* out = (float*)d_out;

  char* ws = (char*)d_ws;
  const size_t MB = 1u << 20;
  u16*   qbf  = (u16*)(ws + 0);
  u16*   kvbf = (u16*)(ws + 16 * MB);
  u16*   wqb  = (u16*)(ws + 32 * MB);
  u16*   wkb  = wqb + 262144;
  u16*   wvb  = wkb + 262144;
  u16*   wob  = wvb + 262144;
  float* qf32 = (float*)(ws + 36 * MB);
  u16*   qpbf = (u16*)(ws + 68 * MB);
  u16*   kbfp = (u16*)(ws + 84 * MB);
  u16*   vtbf = (u16*)(ws + 100 * MB);
  float* xf32 = (float*)(ws + 0);        // reuses qbf+kvbf (dead after projections)
  u16*   xbf  = (u16*)(ws + 100 * MB);   // reuses vtbf     (dead after attention)
  float* yb   = (float*)(ws + 68 * MB);  // reuses qpbf+kbfp (dead after attention)

  const int NTOK = NBATCH * LQ;          // 16384
  dim3 gg(4, NTOK / 128);                // (n-blocks, m-blocks)

  // 1. fp32 -> bf16 (activations, weights)
  cvt2_k<<<8192, 256, 0, stream>>>(query, qbf, keyv, kvbf, NTOK * MSIZE);
  cvt4_k<<<512, 256, 0, stream>>>(Wq, wqb, Wk, wkb, Wv, wvb, Wo, wob, MSIZE * MSIZE);
  // 2-4. projections
  gemm_bt_k<0><<<gg, 256, 0, stream>>>(qbf,  wqb, bq, nullptr, qf32, qpbf);
  gemm_bt_k<1><<<gg, 256, 0, stream>>>(kvbf, wkb, bk, nullptr, nullptr, kbfp);
  gemm_bt_k<2><<<gg, 256, 0, stream>>>(kvbf, wvb, bv, nullptr, nullptr, vtbf);
  // 5. attention + q residual -> d_out used as scratch (pre-LN0)
  attn_k<<<NBATCH * HNUM * (LQ / 32), 64, 0, stream>>>(qpbf, kbfp, vtbf, qf32, out);
  // 6. LN0 -> x (fp32 + bf16)
  ln_kk<1><<<NTOK, 64, 0, stream>>>(out, g0, b0, xf32, xbf);
  // 7. y = x + relu(x @ Wo^T + bo)
  gemm_bt_k<3><<<gg, 256, 0, stream>>>(xbf, wob, bo, xf32, yb, nullptr);
  // 8. LN1 -> final output
  ln_kk<0><<<NTOK, 64, 0, stream>>>(yb, g1, b1, out, nullptr);
}